// Round 1
// baseline (170.958 us; speedup 1.0000x reference)
//
#include <hip/hip_runtime.h>
#include <hip/hip_bf16.h>
#include <cstdint>
#include <cstddef>
#include <math.h>

#define D 256
#define TEMP_INV 2.0f       // 1 / TEMPERATURE, TEMPERATURE = 0.5
#define EPS_NORM 1e-8f

typedef __attribute__((ext_vector_type(8))) short bf16x8;
typedef __attribute__((ext_vector_type(4))) float f32x4;

// ---------------- kernel 1: normalize rows, write bf16 zn ----------------
// one wave per row; 64 lanes x float4 = 256 elements
__global__ void __launch_bounds__(256) normalize_rows(
    const float* __restrict__ zi, const float* __restrict__ zj,
    __hip_bfloat16* __restrict__ zn, int B) {
  int row = blockIdx.x * 4 + (threadIdx.x >> 6);
  int lane = threadIdx.x & 63;
  const float* src = (row < B) ? (zi + (size_t)row * D)
                               : (zj + (size_t)(row - B) * D);
  float4 v = ((const float4*)src)[lane];
  float ss = v.x * v.x + v.y * v.y + v.z * v.z + v.w * v.w;
  for (int off = 32; off; off >>= 1) ss += __shfl_xor(ss, off);
  float rn = 1.0f / fmaxf(sqrtf(ss), EPS_NORM);
  union { ushort4 u; __hip_bfloat16 h[4]; } o;
  o.h[0] = __float2bfloat16(v.x * rn);
  o.h[1] = __float2bfloat16(v.y * rn);
  o.h[2] = __float2bfloat16(v.z * rn);
  o.h[3] = __float2bfloat16(v.w * rn);
  ((ushort4*)zn)[(size_t)row * (D / 4) + lane] = o.u;
}

// ---------------- kernel 2: fused sim GEMM + exp + masked row-sum --------
// 128x128 tile per block, 4 waves in 2x2, each wave 64x64 via 4x4 of
// 16x16x32 bf16 MFMA. K staged in BK=64 chunks via global_load_lds (16B).
__device__ __forceinline__ void load_lds_16B(const __hip_bfloat16* g,
                                             __hip_bfloat16* l) {
  __builtin_amdgcn_global_load_lds(
      (const __attribute__((address_space(1))) void*)g,
      (__attribute__((address_space(3))) void*)l, 16, 0, 0);
}

__global__ void __launch_bounds__(256) ntxent_gemm(
    const __hip_bfloat16* __restrict__ zn,
    float* __restrict__ denom, float* __restrict__ pos, int B) {
  __shared__ __align__(16) __hip_bfloat16 Ash[128 * 64];
  __shared__ __align__(16) __hip_bfloat16 Bsh[128 * 64];

  const int tid = threadIdx.x;
  const int wid = tid >> 6;
  const int lane = tid & 63;
  const int wy = wid >> 1, wx = wid & 1;
  const int bm = blockIdx.y * 128;
  const int bn = blockIdx.x * 128;

  f32x4 acc[4][4] = {};

  // staging geometry: each wave stages 32 rows of A and of B per BK chunk,
  // in 4 wave-ops of 1KB (8 rows x 64 cols bf16). lane -> row l>>3, col (l&7)*8
  const int lrow8 = lane >> 3;
  const int lcol = (lane & 7) * 8;
  const int wrow0 = wid * 32;

  const int frow = lane & 15;   // m/n index within 16x16 frag (input side)
  const int quad = lane >> 4;   // 0..3

  for (int k0 = 0; k0 < D; k0 += 64) {
#pragma unroll
    for (int s = 0; s < 4; ++s) {
      int r = wrow0 + s * 8 + lrow8;
      const __hip_bfloat16* ga = zn + (size_t)(bm + r) * D + k0 + lcol;
      const __hip_bfloat16* gb = zn + (size_t)(bn + r) * D + k0 + lcol;
      // wave-uniform LDS base; HW adds lane*16B
      load_lds_16B(ga, &Ash[(wrow0 + s * 8) * 64]);
      load_lds_16B(gb, &Bsh[(wrow0 + s * 8) * 64]);
    }
    __syncthreads();
#pragma unroll
    for (int kk = 0; kk < 2; ++kk) {
      const int koff = kk * 32 + quad * 8;
      bf16x8 a[4], b[4];
#pragma unroll
      for (int i = 0; i < 4; ++i)
        a[i] = *(const bf16x8*)&Ash[(wy * 64 + i * 16 + frow) * 64 + koff];
#pragma unroll
      for (int j = 0; j < 4; ++j)
        b[j] = *(const bf16x8*)&Bsh[(wx * 64 + j * 16 + frow) * 64 + koff];
#pragma unroll
      for (int i = 0; i < 4; ++i)
#pragma unroll
        for (int j = 0; j < 4; ++j)
          acc[i][j] =
              __builtin_amdgcn_mfma_f32_16x16x32_bf16(a[i], b[j], acc[i][j], 0, 0, 0);
    }
    __syncthreads();
  }

  // epilogue: C/D layout col = lane&15, row = quad*4 + reg
  const int colq = lane & 15;
#pragma unroll
  for (int i = 0; i < 4; ++i) {
#pragma unroll
    for (int r = 0; r < 4; ++r) {
      int row = bm + wy * 64 + i * 16 + quad * 4 + r;
      float rs = 0.0f;
#pragma unroll
      for (int j = 0; j < 4; ++j) {
        int col = bn + wx * 64 + j * 16 + colq;
        float v = acc[i][j][r];
        if (col != row) rs += __expf(v * TEMP_INV);
        if (col == row + B || col + B == row) pos[row] = v;  // exactly one writer
      }
      rs += __shfl_xor(rs, 1);
      rs += __shfl_xor(rs, 2);
      rs += __shfl_xor(rs, 4);
      rs += __shfl_xor(rs, 8);
      if (colq == 0) atomicAdd(&denom[row], rs);
    }
  }
}

// ---------------- kernel 3: finalize loss scalar -------------------------
__global__ void __launch_bounds__(256) finalize(
    const float* __restrict__ denom, const float* __restrict__ pos,
    float* __restrict__ out, int N) {
  __shared__ float red[256];
  float s = 0.0f;
  for (int i = threadIdx.x; i < N; i += 256)
    s += logf(denom[i]) - pos[i] * TEMP_INV;
  red[threadIdx.x] = s;
  __syncthreads();
  for (int off = 128; off; off >>= 1) {
    if ((int)threadIdx.x < off) red[threadIdx.x] += red[threadIdx.x + off];
    __syncthreads();
  }
  if (threadIdx.x == 0) out[0] = red[0] / (float)N;
}

extern "C" void kernel_launch(void* const* d_in, const int* in_sizes, int n_in,
                              void* d_out, int out_size, void* d_ws, size_t ws_size,
                              hipStream_t stream) {
  const float* zi = (const float*)d_in[0];
  const float* zj = (const float*)d_in[1];
  const int B = in_sizes[0] / D;  // 4096
  const int N = 2 * B;            // 8192

  __hip_bfloat16* zn = (__hip_bfloat16*)d_ws;
  float* denom = (float*)((char*)d_ws + (size_t)N * D * sizeof(__hip_bfloat16));
  float* pos = denom + N;

  hipMemsetAsync(denom, 0, (size_t)N * sizeof(float), stream);
  normalize_rows<<<N / 4, 256, 0, stream>>>(zi, zj, zn, B);
  dim3 grid(N / 128, N / 128);
  ntxent_gemm<<<grid, 256, 0, stream>>>(zn, denom, pos, B);
  finalize<<<1, 256, 0, stream>>>(denom, pos, (float*)d_out, N);
}